// Round 10
// baseline (11385.056 us; speedup 1.0000x reference)
//
#include <hip/hip_runtime.h>

#define NN   729
#define NF   730   // N+1
#define BV   8
#define KK   32
#define NBAS 40
#define MAXIT 10
#define PI_F 3.14159265358979323846f

#define MTH   1024  // mix threads (16 waves = 4 waves/EU, one block/CU)
#define BT    16    // steps per block
#define AST   448   // padded max active rows; CactT stride
#define NSLOT 60    // bulk row slots (960 lanes / 16 lanes-per-row)
#define NPASS 8     // 60*8 = 480 >= 448
// LDS pad: push total LDS past 81920 so only ONE block fits per CU.
#define VPAD  2176

typedef float v2f __attribute__((ext_vector_type(2)));

__device__ __forceinline__ v2f fma2(float c, v2f d, v2f w) {
    w.x = fmaf(c, d.x, w.x);
    w.y = fmaf(c, d.y, w.y);
    return w;
}

// ---------------- build Ct (730x730), Ct[i][j] = C[j][i] ----------------
__global__ void build_C_kernel(const float* __restrict__ coeff,
                               const float* __restrict__ upper,
                               const float* __restrict__ basis,
                               float* __restrict__ Ct) {
    int idx = blockIdx.x * blockDim.x + threadIdx.x;
    if (idx >= NF * NF) return;
    int i = idx / NF, j = idx - i * NF;   // (i,j) of C; coalesced basis reads
    float val;
    if (i == 0) {
        val = (j == 0) ? 0.f : upper[j - 1];
    } else if (j == 0) {
        val = upper[i - 1];
    } else {
        float acc = 0.f;
        const float* bp = basis + (size_t)(i - 1) * NN + (j - 1);
        #pragma unroll 8
        for (int b = 0; b < NBAS; ++b)
            acc = fmaf(coeff[b], bp[(size_t)b * NN * NN], acc);
        val = acc;
    }
    Ct[(size_t)j * NF + i] = val;
}

// ---------------- init V  (B x 730 x 32) ----------------
__global__ void init_V_kernel(const float* __restrict__ z,
                              const float* __restrict__ vraw,
                              float* __restrict__ V) {
    int g = threadIdx.x >> 5;
    int k = threadIdx.x & 31;
    int row = blockIdx.x * 8 + g;           // 0..5839
    int b = row / NF, n = row - b * NF;
    const float* vr = vraw + (size_t)b * NF * KK;

    float v0 = vr[k];
    float s2 = v0 * v0;
    #pragma unroll
    for (int off = 16; off; off >>= 1) s2 += __shfl_xor(s2, off, 32);
    v0 = v0 / sqrtf(s2);

    float vn = vr[(size_t)n * KK + k];
    float d = vn * v0;
    #pragma unroll
    for (int off = 16; off; off >>= 1) d += __shfl_xor(d, off, 32);
    float u = vn - d * v0;
    float un2 = u * u;
    #pragma unroll
    for (int off = 16; off; off >>= 1) un2 += __shfl_xor(un2, off, 32);
    u = u / fmaxf(sqrtf(un2), 1e-8f);

    float zf = (n == 0) ? 1.f : z[b * NN + (n - 1)];
    float c = cosf(PI_F * zf), s = sinf(PI_F * zf);
    float outv = -c * v0 + s * u;
    if (n == 0) outv = v0;
    V[((size_t)b * NF + n) * KK + k] = outv;
}

// ---------------- build per-batch active lists (perm order) ----------------
__global__ void build_act_kernel(const int* __restrict__ is_input,
                                 const int* __restrict__ perm,
                                 int* __restrict__ act, int* __restrict__ nA_arr) {
    int b = blockIdx.x, l = threadIdx.x;   // 64 threads = 1 wave
    int base = 0;
    for (int c = 0; c < (NN + 63) / 64; ++c) {
        int idx = c * 64 + l;
        bool f = false; int pi = 0;
        if (idx < NN) { pi = perm[idx]; f = (is_input[b * NN + pi - 1] == 0); }
        unsigned long long m = __ballot(f);
        int pos = __popcll(m & ((1ull << l) - 1ull));
        if (f && base + pos < AST) act[b * AST + base + pos] = pi;
        base += __popcll(m);
    }
    if (base > AST) base = AST;
    if (l == 0) nA_arr[b] = base;
    for (int p = base + l; p < AST; p += 64) act[b * AST + p] = 0;
}

// --- gather CactT[b][a][t] = C[r_t][r_a] = Ct[r_a][r_t] (row-coalesced) ---
__global__ void gather_CactT_kernel(const float* __restrict__ Ct,
                                    const int* __restrict__ act,
                                    float* __restrict__ CactT) {
    int a = blockIdx.x, b = blockIdx.y;
    __shared__ int acts[AST];
    for (int i = threadIdx.x; i < AST; i += blockDim.x) acts[i] = act[b * AST + i];
    __syncthreads();
    const float* src = Ct + (size_t)acts[a] * NF;
    float* dst = CactT + ((size_t)b * AST + a) * AST;
    for (int t = threadIdx.x; t < AST; t += blockDim.x)
        dst[t] = src[acts[t]];
}

// ------- init W (compact): W[a] = sum_j Ct[ra][j] V[j] - Cd V[ra] -------
__global__ void init_W_kernel(const float* __restrict__ Ct,
                              const int* __restrict__ act,
                              const int* __restrict__ nA_arr,
                              const float* __restrict__ V,
                              float* __restrict__ Wc) {
    int b = blockIdx.y;
    int a = blockIdx.x * 8 + (threadIdx.x >> 5);
    int k = threadIdx.x & 31;
    int nA = nA_arr[b];
    float w = 0.f;
    if (a < nA) {
        int ra = act[b * AST + a];
        const float* ctr = Ct + (size_t)ra * NF;
        const float* vb = V + (size_t)b * NF * KK + k;
        float acc = 0.f;
        for (int j = 0; j < NF; ++j)
            acc = fmaf(ctr[j], vb[(size_t)j * KK], acc);
        float cd = ctr[ra];
        w = acc - cd * V[((size_t)b * NF + ra) * KK + k];
    }
    Wc[((size_t)b * AST + a) * KK + k] = w;
}

// 16-lane row sum via DPP row rotations (pure VALU)
__device__ __forceinline__ float rowsum16(float x) {
    int y;
    y = __builtin_amdgcn_update_dpp(0, __float_as_int(x), 0x121, 0xF, 0xF, false);
    x += __int_as_float(y);
    y = __builtin_amdgcn_update_dpp(0, __float_as_int(x), 0x122, 0xF, 0xF, false);
    x += __int_as_float(y);
    y = __builtin_amdgcn_update_dpp(0, __float_as_int(x), 0x124, 0xF, 0xF, false);
    x += __int_as_float(y);
    y = __builtin_amdgcn_update_dpp(0, __float_as_int(x), 0x128, 0xF, 0xF, false);
    x += __int_as_float(y);
    return x;
}

// ---------------- mixing: W in registers, 2-barrier 16-step blocks --------
// Bulk restructured for <=64-VGPR demand (the allocator pins 64 here and
// R6-R9 spilled ~40 regs to scratch: WRITE_SIZE 1 MB, 6x slowdown):
// rank-16 split into two rank-8 halves; dvv[8] re-read per half; c loaded
// per pass as 2 float4 (no ping-pong arrays).
__global__ __launch_bounds__(MTH) __attribute__((amdgpu_waves_per_eu(4, 4)))
void mix_kernel(const float* __restrict__ CactT_g,
                const float* __restrict__ Wc,
                const int* __restrict__ act_g,
                const int* __restrict__ nA_arr,
                const int* __restrict__ is_input,
                const float* __restrict__ z,
                const float* __restrict__ Vg,
                float* __restrict__ out) {
    __shared__ float V_c[AST * KK + VPAD]; // 66048 B (VPAD pushes LDS > 80 KB)
    __shared__ float gpub[BT * KK];        // 2048 B
    __shared__ float dv_s[2][BT * KK];     // 4096 B
    __shared__ float cblk_s[2][BT * BT];   // 2048 B
    __shared__ float cmini_s[2][BT * BT];  // 2048 B
    __shared__ float Cd_s[AST];            // 1792 B
    __shared__ int   act_s[AST];           // 1792 B
    __shared__ int   slot_s[NF];           // 2920 B

    int b = blockIdx.x, tid = threadIdx.x;
    const float* CactT_b = CactT_g + (size_t)b * AST * AST;
    int nA = nA_arr[b];
    int nblkp = (nA + BT - 1) / BT;
    if (nblkp < 2) nblkp = 2;
    int nAp = nblkp * BT;
    int totB = MAXIT * nblkp;

    int wid = tid >> 6;
    bool isbulk = (tid >= 64);
    int lane = isbulk ? (tid - 64) : 0;
    int kp = lane & 15;           // k-pair index: floats 2kp, 2kp+1
    int slot = lane >> 4;         // 0..59

    // ---- setup ----
    if (tid < AST) act_s[tid] = act_g[b * AST + tid];
    __syncthreads();
    for (int idx = tid; idx < nAp * KK; idx += MTH)
        V_c[idx] = Vg[((size_t)b * NF + act_s[idx >> 5]) * KK + (idx & 31)];
    if (tid < nA) slot_s[act_s[tid]] = tid;
    if (tid < AST) Cd_s[tid] = CactT_b[(size_t)tid * AST + tid];
    if (tid < 256) {   // cblk for block 0: cblk[t*16+u] = CactT[u][t]
        int t = tid >> 4, u = tid & 15;
        cblk_s[0][t * BT + u] = CactT_b[(size_t)u * AST + t];
    }
    // keep the pad region live so LDS allocation isn't shrunk
    if (tid == 0) V_c[AST * KK + VPAD - 1] = 0.f;
    // W rows into registers: lane owns rows a = slot + 60p, element pair kp
    v2f w[NPASS];
    #pragma unroll
    for (int p = 0; p < NPASS; ++p) {
        int a = slot + NSLOT * p;
        v2f zz = {0.f, 0.f};
        w[p] = zz;
        if (isbulk && a < AST)
            w[p] = *(const v2f*)&Wc[((size_t)b * AST + a) * KK + 2 * kp];
    }
    __syncthreads();

    for (int bi = 0; bi < totB; ++bi) {
        int blk = bi % nblkp, s0 = blk * BT;
        int pblk = (bi - 1 + nblkp) % nblkp, sp0 = pblk * BT;  // junk at bi=0
        int cb = bi & 1, pv = cb ^ 1;
        int sn0 = ((bi + 1) % nblkp) * BT;

        // ---- phase 1: owners of current block apply prev dv + publish ----
        if (isbulk) {
            #pragma unroll
            for (int p = 0; p < NPASS; ++p) {
                int a = slot + NSLOT * p;
                if ((a >> 4) == blk) {
                    int u = a - s0;
                    if (bi > 0) {
                        #pragma unroll
                        for (int t = 0; t < BT; ++t) {
                            float c = cmini_s[cb][u * BT + t];
                            v2f d = *(const v2f*)&dv_s[pv][t * KK + 2 * kp];
                            w[p] = fma2(c, d, w[p]);
                        }
                    }
                    *(v2f*)&gpub[u * KK + 2 * kp] = w[p];
                }
            }
        }
        __syncthreads();

        // ---- phase 2: serial (wave 0) || bulk sweep (waves 1-15) ----
        if (wid == 0) {
            int ll = tid & 15;
            float g0[BT], g1[BT];
            #pragma unroll
            for (int u = 0; u < BT; ++u) {
                g0[u] = gpub[u * KK + ll];
                g1[u] = gpub[u * KK + ll + 16];
            }
            #pragma unroll
            for (int u = 0; u < BT; ++u) {
                int s = s0 + u;
                float n2 = fmaf(g0[u], g0[u], g1[u] * g1[u]);
                n2 = rowsum16(n2);
                float inv = -__builtin_amdgcn_rsqf(fmaxf(n2, 1e-16f));
                float vo0 = V_c[s * KK + ll];
                float vo1 = V_c[s * KK + ll + 16];
                float msk = (s < nA) ? 1.f : 0.f;
                float d0 = fmaf(g0[u], inv, -vo0) * msk;
                float d1 = fmaf(g1[u], inv, -vo1) * msk;
                if (tid < 16) {
                    dv_s[cb][u * KK + ll]      = d0;
                    dv_s[cb][u * KK + ll + 16] = d1;
                    V_c[s * KK + ll]      = vo0 + d0;
                    V_c[s * KK + ll + 16] = vo1 + d1;
                }
                #pragma unroll
                for (int u2 = u + 1; u2 < BT; ++u2) {
                    float c = cblk_s[cb][u * BT + u2];
                    g0[u2] = fmaf(c, d0, g0[u2]);
                    g1[u2] = fmaf(c, d1, g1[u2]);
                }
            }
        } else {
            // stagers for next iteration's tiles
            if (wid == 14) {   // cmini: rows of next block x cols of this block
                int l = tid & 63; int u = l & 15, q = l >> 4;
                float4 v = *(const float4*)&CactT_b[(size_t)(sn0 + u) * AST + s0 + 4 * q];
                *(float4*)&cmini_s[pv][u * BT + 4 * q] = v;
            }
            if (wid == 15) {   // cblk: next block's intra tile (transposed store)
                int l = tid & 63; int u = l & 15, q = l >> 4;
                float4 v = *(const float4*)&CactT_b[(size_t)(sn0 + u) * AST + sn0 + 4 * q];
                cblk_s[pv][(4 * q + 0) * BT + u] = v.x;
                cblk_s[pv][(4 * q + 1) * BT + u] = v.y;
                cblk_s[pv][(4 * q + 2) * BT + u] = v.z;
                cblk_s[pv][(4 * q + 3) * BT + u] = v.w;
            }
            // bulk: apply prev dv to all owned rows except current block,
            // two rank-8 halves to keep register demand under 64
            if (bi > 0) {
                #pragma unroll
                for (int h = 0; h < 2; ++h) {
                    v2f dvv[8];
                    #pragma unroll
                    for (int t = 0; t < 8; ++t)
                        dvv[t] = *(const v2f*)&dv_s[pv][(8 * h + t) * KK + 2 * kp];
                    const float* cbase = CactT_b + sp0 + 8 * h;
                    #pragma unroll
                    for (int p = 0; p < NPASS; ++p) {
                        int a = slot + NSLOT * p;
                        const float* cr = cbase + (size_t)a * AST;
                        float4 ca = *(const float4*)(cr);
                        float4 cbq = *(const float4*)(cr + 4);
                        if (a < nAp && (a >> 4) != blk) {
                            w[p] = fma2(ca.x,  dvv[0], w[p]);
                            w[p] = fma2(ca.y,  dvv[1], w[p]);
                            w[p] = fma2(ca.z,  dvv[2], w[p]);
                            w[p] = fma2(ca.w,  dvv[3], w[p]);
                            w[p] = fma2(cbq.x, dvv[4], w[p]);
                            w[p] = fma2(cbq.y, dvv[5], w[p]);
                            w[p] = fma2(cbq.z, dvv[6], w[p]);
                            w[p] = fma2(cbq.w, dvv[7], w[p]);
                        }
                    }
                }
                // diag self-cancel for rows of the previous block
                #pragma unroll
                for (int p = 0; p < NPASS; ++p) {
                    int a = slot + NSLOT * p;
                    if ((a >> 4) == pblk) {
                        v2f dd = *(const v2f*)&dv_s[pv][(a - sp0) * KK + 2 * kp];
                        w[p] = fma2(-Cd_s[a], dd, w[p]);
                    }
                }
            }
        }
        __syncthreads();
    }

    // ---- epilogue: z_out ----
    int k = tid & 31, r = tid >> 5;
    float v0k = Vg[(size_t)b * NF * KK + k];
    for (int n = 1 + r; n <= NN; n += 32) {
        int ii = is_input[b * NN + n - 1];
        float res;
        if (ii == 1) {
            res = z[b * NN + n - 1];
        } else {
            int a = slot_s[n];
            float dot = V_c[a * KK + k] * v0k;
            #pragma unroll
            for (int off = 16; off; off >>= 1) dot += __shfl_xor(dot, off, 32);
            float ca = fminf(fmaxf(-dot, -1.f + 1e-6f), 1.f - 1e-6f);
            res = acosf(ca) * (1.f / PI_F);
        }
        if (k == 0) out[b * NN + n - 1] = res;
    }
}

extern "C" void kernel_launch(void* const* d_in, const int* in_sizes, int n_in,
                              void* d_out, int out_size, void* d_ws, size_t ws_size,
                              hipStream_t stream) {
    const float* coeff    = (const float*)d_in[0];
    const float* upper    = (const float*)d_in[1];
    const float* basis    = (const float*)d_in[2];
    const float* z        = (const float*)d_in[3];
    const int*   is_input = (const int*)d_in[4];
    const float* vraw     = (const float*)d_in[5];
    const int*   perm     = (const int*)d_in[6];
    float* out = (float*)d_out;

    float* ws    = (float*)d_ws;
    float* Ct    = ws;                              // 730*730
    float* V     = Ct + (size_t)NF * NF;            // 8*730*32
    float* CactT = V + (size_t)BV * NF * KK;        // 8*448*448
    float* Wc    = CactT + (size_t)BV * AST * AST;  // 8*448*32
    int*   act   = (int*)(Wc + (size_t)BV * AST * KK);  // 8*448
    int*   nAa   = act + BV * AST;                  // 8
    // total ws ≈ 9.8 MB

    build_C_kernel<<<dim3((NF * NF + 255) / 256), dim3(256), 0, stream>>>(coeff, upper, basis, Ct);
    init_V_kernel<<<dim3(730), dim3(256), 0, stream>>>(z, vraw, V);
    build_act_kernel<<<dim3(BV), dim3(64), 0, stream>>>(is_input, perm, act, nAa);
    gather_CactT_kernel<<<dim3(AST, BV), dim3(256), 0, stream>>>(Ct, act, CactT);
    init_W_kernel<<<dim3(AST / 8, BV), dim3(256), 0, stream>>>(Ct, act, nAa, V, Wc);
    mix_kernel<<<dim3(BV), dim3(MTH), 0, stream>>>(CactT, Wc, act, nAa, is_input, z, V, out);
}

// Round 11
// 1981.176 us; speedup vs baseline: 5.7466x; 5.7466x over previous
//
#include <hip/hip_runtime.h>

#define NN   729
#define NF   730   // N+1
#define BV   8
#define KK   32
#define NBAS 40
#define MAXIT 10
#define PI_F 3.14159265358979323846f

#define MTH   1024  // mix threads (16 waves)
#define BT    16    // steps per block
#define AST   448   // padded max active rows; CactT stride
#define WST2  34    // W_c row stride (floats): rows shift banks by 2 -> b64 conflict-free

typedef float v2f __attribute__((ext_vector_type(2)));

__device__ __forceinline__ v2f fma2(float c, v2f d, v2f w) {
    w.x = fmaf(c, d.x, w.x);
    w.y = fmaf(c, d.y, w.y);
    return w;
}

// ---------------- build Ct (730x730), Ct[i][j] = C[j][i] ----------------
__global__ void build_C_kernel(const float* __restrict__ coeff,
                               const float* __restrict__ upper,
                               const float* __restrict__ basis,
                               float* __restrict__ Ct) {
    int idx = blockIdx.x * blockDim.x + threadIdx.x;
    if (idx >= NF * NF) return;
    int i = idx / NF, j = idx - i * NF;
    float val;
    if (i == 0) {
        val = (j == 0) ? 0.f : upper[j - 1];
    } else if (j == 0) {
        val = upper[i - 1];
    } else {
        float acc = 0.f;
        const float* bp = basis + (size_t)(i - 1) * NN + (j - 1);
        #pragma unroll 8
        for (int b = 0; b < NBAS; ++b)
            acc = fmaf(coeff[b], bp[(size_t)b * NN * NN], acc);
        val = acc;
    }
    Ct[(size_t)j * NF + i] = val;
}

// ---------------- init V  (B x 730 x 32) ----------------
__global__ void init_V_kernel(const float* __restrict__ z,
                              const float* __restrict__ vraw,
                              float* __restrict__ V) {
    int g = threadIdx.x >> 5;
    int k = threadIdx.x & 31;
    int row = blockIdx.x * 8 + g;           // 0..5839
    int b = row / NF, n = row - b * NF;
    const float* vr = vraw + (size_t)b * NF * KK;

    float v0 = vr[k];
    float s2 = v0 * v0;
    #pragma unroll
    for (int off = 16; off; off >>= 1) s2 += __shfl_xor(s2, off, 32);
    v0 = v0 / sqrtf(s2);

    float vn = vr[(size_t)n * KK + k];
    float d = vn * v0;
    #pragma unroll
    for (int off = 16; off; off >>= 1) d += __shfl_xor(d, off, 32);
    float u = vn - d * v0;
    float un2 = u * u;
    #pragma unroll
    for (int off = 16; off; off >>= 1) un2 += __shfl_xor(un2, off, 32);
    u = u / fmaxf(sqrtf(un2), 1e-8f);

    float zf = (n == 0) ? 1.f : z[b * NN + (n - 1)];
    float c = cosf(PI_F * zf), s = sinf(PI_F * zf);
    float outv = -c * v0 + s * u;
    if (n == 0) outv = v0;
    V[((size_t)b * NF + n) * KK + k] = outv;
}

// ---------------- build per-batch active lists (perm order) ----------------
__global__ void build_act_kernel(const int* __restrict__ is_input,
                                 const int* __restrict__ perm,
                                 int* __restrict__ act, int* __restrict__ nA_arr) {
    int b = blockIdx.x, l = threadIdx.x;   // 64 threads = 1 wave
    int base = 0;
    for (int c = 0; c < (NN + 63) / 64; ++c) {
        int idx = c * 64 + l;
        bool f = false; int pi = 0;
        if (idx < NN) { pi = perm[idx]; f = (is_input[b * NN + pi - 1] == 0); }
        unsigned long long m = __ballot(f);
        int pos = __popcll(m & ((1ull << l) - 1ull));
        if (f && base + pos < AST) act[b * AST + base + pos] = pi;
        base += __popcll(m);
    }
    if (base > AST) base = AST;
    if (l == 0) nA_arr[b] = base;
    for (int p = base + l; p < AST; p += 64) act[b * AST + p] = 0;
}

// --- gather CactT[b][a][t] = C[r_t][r_a] = Ct[r_a][r_t] (row-coalesced) ---
__global__ void gather_CactT_kernel(const float* __restrict__ Ct,
                                    const int* __restrict__ act,
                                    float* __restrict__ CactT) {
    int a = blockIdx.x, b = blockIdx.y;
    __shared__ int acts[AST];
    for (int i = threadIdx.x; i < AST; i += blockDim.x) acts[i] = act[b * AST + i];
    __syncthreads();
    const float* src = Ct + (size_t)acts[a] * NF;
    float* dst = CactT + ((size_t)b * AST + a) * AST;
    for (int t = threadIdx.x; t < AST; t += blockDim.x)
        dst[t] = src[acts[t]];
}

// --- init W compact + compact V copy ---
__global__ void init_W_kernel(const float* __restrict__ Ct,
                              const int* __restrict__ act,
                              const int* __restrict__ nA_arr,
                              const float* __restrict__ V,
                              float* __restrict__ Wc,
                              float* __restrict__ Vact) {
    int b = blockIdx.y;
    int a = blockIdx.x * 8 + (threadIdx.x >> 5);
    int k = threadIdx.x & 31;
    int nA = nA_arr[b];
    float w = 0.f;
    int ra = act[b * AST + a];
    float vv = V[((size_t)b * NF + ra) * KK + k];
    if (a < nA) {
        const float* ctr = Ct + (size_t)ra * NF;
        const float* vb = V + (size_t)b * NF * KK + k;
        float acc = 0.f;
        for (int j = 0; j < NF; ++j)
            acc = fmaf(ctr[j], vb[(size_t)j * KK], acc);
        w = acc - ctr[ra] * vv;
    }
    Wc[((size_t)b * AST + a) * KK + k] = w;
    Vact[((size_t)b * AST + a) * KK + k] = vv;
}

// 16-lane row sum via DPP row rotations (pure VALU)
__device__ __forceinline__ float rowsum16(float x) {
    int y;
    y = __builtin_amdgcn_update_dpp(0, __float_as_int(x), 0x121, 0xF, 0xF, false);
    x += __int_as_float(y);
    y = __builtin_amdgcn_update_dpp(0, __float_as_int(x), 0x122, 0xF, 0xF, false);
    x += __int_as_float(y);
    y = __builtin_amdgcn_update_dpp(0, __float_as_int(x), 0x124, 0xF, 0xF, false);
    x += __int_as_float(y);
    y = __builtin_amdgcn_update_dpp(0, __float_as_int(x), 0x128, 0xF, 0xF, false);
    x += __int_as_float(y);
    return x;
}

// ---------------- mixing: W in LDS, c-panel LDS-staged, V global ----------
__global__ __launch_bounds__(MTH)
void mix_kernel(const float* __restrict__ CactT_g,
                const float* __restrict__ Wc_g,
                float* __restrict__ Vact_g,
                const int* __restrict__ act_g,
                const int* __restrict__ nA_arr,
                const int* __restrict__ is_input,
                const float* __restrict__ z,
                const float* __restrict__ Vg,
                float* __restrict__ out) {
    __shared__ float W_c[AST * WST2];       // 60928 B
    __shared__ float cpanel[2][AST * BT];   // 57344 B
    __shared__ float dv_s[2][BT * KK];      // 4096 B
    __shared__ float cblk_s[2][BT * BT];    // 2048 B
    __shared__ float Cd_s[AST];             // 1792 B
    __shared__ int   slot_s[NF];            // 2920 B  -> total 129128 B

    int b = blockIdx.x, tid = threadIdx.x;
    const float* CT = CactT_g + (size_t)b * AST * AST;
    float* Vact = Vact_g + (size_t)b * AST * KK;
    int nA = nA_arr[b];
    int nblkp = (nA + BT - 1) / BT;
    if (nblkp < 2) nblkp = 2;
    int nAp = nblkp * BT;
    int totB = MAXIT * nblkp;

    int wid = tid >> 6;
    int l64 = tid & 63;
    int kp = tid & 15;            // k-pair (floats 2kp, 2kp+1)
    int rsub = (tid >> 4) & 3;    // row-sub within wave-step
    int rbase = (wid - 1) * 4 + rsub;   // bulk row offset within a 60-row wstep

    // ---- setup ----
    for (int idx = tid; idx < AST * KK; idx += MTH)
        W_c[(idx >> 5) * WST2 + (idx & 31)] = Wc_g[((size_t)b * AST) * KK + idx];
    if (tid < AST) Cd_s[tid] = CT[(size_t)tid * AST + tid];
    if (tid < nA) slot_s[act_g[b * AST + tid]] = tid;
    if (tid < 256)   // cblk for block 0: cblk[u*16+u2] = CT[u2][u]
        cblk_s[0][tid] = CT[(size_t)(tid & 15) * AST + (tid >> 4)];
    __syncthreads();

    // stage-lane mapping for cpanel (waves 1..14 cover rows 0..447)
    int srow = (wid - 1) * 32 + (l64 >> 2);
    int sq = (l64 & 3) * 4;

    for (int bi = 0; bi < totB; ++bi) {
        int blk = bi % nblkp, s0 = blk * BT;
        int pblk = (bi - 1 + nblkp) % nblkp;          // junk at bi=0
        int cb = bi & 1, pv = cb ^ 1;
        int sn0 = ((bi + 1) % nblkp) * BT;
        int wsA = s0 / 60, wsB = (s0 + BT - 1) / 60;

        v2f dvv[BT];
        v2f vr0, vr1, vr2, vr3, vr4, vr5, vr6, vr7;   // serial V ring
        if (wid == 0) {
            const float* vp = Vact + (size_t)s0 * KK + 2 * kp;
            vr0 = *(const v2f*)(vp);        vr1 = *(const v2f*)(vp + KK);
            vr2 = *(const v2f*)(vp + 2*KK); vr3 = *(const v2f*)(vp + 3*KK);
            vr4 = *(const v2f*)(vp + 4*KK); vr5 = *(const v2f*)(vp + 5*KK);
            vr6 = *(const v2f*)(vp + 6*KK); vr7 = *(const v2f*)(vp + 7*KK);
        } else if (bi > 0) {
            #pragma unroll
            for (int t = 0; t < BT; ++t)
                dvv[t] = *(const v2f*)&dv_s[pv][t * KK + 2 * kp];
            // ---- phase A: update rows of the CURRENT block ----
            for (int ws = wsA; ws <= wsB; ++ws) {
                int row = ws * 60 + rbase;
                if (row >= s0 && row < s0 + BT) {
                    v2f w = *(const v2f*)&W_c[row * WST2 + 2 * kp];
                    #pragma unroll
                    for (int q = 0; q < 4; ++q) {
                        float4 c = *(const float4*)&cpanel[cb][row * BT + 4 * q];
                        w = fma2(c.x, dvv[4*q+0], w);
                        w = fma2(c.y, dvv[4*q+1], w);
                        w = fma2(c.z, dvv[4*q+2], w);
                        w = fma2(c.w, dvv[4*q+3], w);
                    }
                    *(v2f*)&W_c[row * WST2 + 2 * kp] = w;
                }
            }
        }
        __syncthreads();

        if (wid == 0) {
            // ---- serial: 16 steps, eager corrections, V from global ring ----
            float g0[BT], g1[BT];
            #pragma unroll
            for (int u = 0; u < BT; ++u) {
                v2f gv = *(const v2f*)&W_c[(s0 + u) * WST2 + 2 * kp];
                g0[u] = gv.x; g1[u] = gv.y;
            }
            #pragma unroll
            for (int u = 0; u < BT; ++u) {
                int s = s0 + u;
                float n2 = fmaf(g0[u], g0[u], g1[u] * g1[u]);
                n2 = rowsum16(n2);
                float inv = -__builtin_amdgcn_rsqf(fmaxf(n2, 1e-16f));
                v2f vo;
                switch (u & 7) {
                    case 0: vo = vr0; break; case 1: vo = vr1; break;
                    case 2: vo = vr2; break; case 3: vo = vr3; break;
                    case 4: vo = vr4; break; case 5: vo = vr5; break;
                    case 6: vo = vr6; break; default: vo = vr7; break;
                }
                if (u < 8) {   // prefetch step u+8 into freed slot
                    const v2f* np = (const v2f*)&Vact[(size_t)(s0 + u + 8) * KK + 2 * kp];
                    switch (u & 7) {
                        case 0: vr0 = *np; break; case 1: vr1 = *np; break;
                        case 2: vr2 = *np; break; case 3: vr3 = *np; break;
                        case 4: vr4 = *np; break; case 5: vr5 = *np; break;
                        case 6: vr6 = *np; break; default: vr7 = *np; break;
                    }
                }
                float msk = (s < nA) ? 1.f : 0.f;
                float d0 = fmaf(g0[u], inv, -vo.x) * msk;
                float d1 = fmaf(g1[u], inv, -vo.y) * msk;
                if (tid < 16) {
                    v2f dv2; dv2.x = d0; dv2.y = d1;
                    *(v2f*)&dv_s[cb][u * KK + 2 * kp] = dv2;
                    v2f vn2; vn2.x = vo.x + d0; vn2.y = vo.y + d1;
                    *(v2f*)&Vact[(size_t)s * KK + 2 * kp] = vn2;
                }
                #pragma unroll
                for (int u2 = u + 1; u2 < BT; ++u2) {
                    float c = cblk_s[cb][u * BT + u2];
                    g0[u2] = fmaf(c, d0, g0[u2]);
                    g1[u2] = fmaf(c, d1, g1[u2]);
                }
            }
        } else {
            // issue next-iter cpanel loads early (cols = current block s0)
            float4 sg0, sg1;
            bool dostage = (wid <= 14);
            if (dostage) {
                const float* p0 = CT + (size_t)srow * AST + s0 + sq;
                sg0 = *(const float4*)p0;
                sg1 = *(const float4*)(p0 + (size_t)16 * AST);
            }
            // ---- phase B: update all other rows ----
            if (bi > 0) {
                for (int ws = 0; ws < 8; ++ws) {
                    int row = ws * 60 + rbase;
                    bool inblk = (row >= s0 && row < s0 + BT);
                    if (row < nAp && !inblk) {
                        v2f w = *(const v2f*)&W_c[row * WST2 + 2 * kp];
                        #pragma unroll
                        for (int q = 0; q < 4; ++q) {
                            float4 c = *(const float4*)&cpanel[cb][row * BT + 4 * q];
                            w = fma2(c.x, dvv[4*q+0], w);
                            w = fma2(c.y, dvv[4*q+1], w);
                            w = fma2(c.z, dvv[4*q+2], w);
                            w = fma2(c.w, dvv[4*q+3], w);
                        }
                        if ((row >> 4) == pblk) {   // diag self-cancel (LDS re-read)
                            v2f dd = *(const v2f*)&dv_s[pv][(row & 15) * KK + 2 * kp];
                            w = fma2(-Cd_s[row], dd, w);
                        }
                        *(v2f*)&W_c[row * WST2 + 2 * kp] = w;
                    }
                }
            }
            // write staged cpanel (late)
            if (dostage) {
                *(float4*)&cpanel[pv][srow * BT + sq] = sg0;
                *(float4*)&cpanel[pv][(srow + 16) * BT + sq] = sg1;
            }
            if (wid == 15) {   // stage next block's intra tile
                #pragma unroll
                for (int qq = 0; qq < 4; ++qq) {
                    int idx = qq * 64 + l64;   // idx = u*16+u2
                    cblk_s[pv][idx] =
                        CT[(size_t)(sn0 + (idx & 15)) * AST + sn0 + (idx >> 4)];
                }
            }
        }
        __syncthreads();
    }

    // ---- epilogue: z_out (Vact stores drained by the loop's final barrier) ----
    int k = tid & 31, r = tid >> 5;
    float v0k = Vg[(size_t)b * NF * KK + k];
    for (int n = 1 + r; n <= NN; n += 32) {
        int ii = is_input[b * NN + n - 1];
        float res;
        if (ii == 1) {
            res = z[b * NN + n - 1];
        } else {
            int a = slot_s[n];
            float dot = Vact[(size_t)a * KK + k] * v0k;
            #pragma unroll
            for (int off = 16; off; off >>= 1) dot += __shfl_xor(dot, off, 32);
            float ca = fminf(fmaxf(-dot, -1.f + 1e-6f), 1.f - 1e-6f);
            res = acosf(ca) * (1.f / PI_F);
        }
        if (k == 0) out[b * NN + n - 1] = res;
    }
}

extern "C" void kernel_launch(void* const* d_in, const int* in_sizes, int n_in,
                              void* d_out, int out_size, void* d_ws, size_t ws_size,
                              hipStream_t stream) {
    const float* coeff    = (const float*)d_in[0];
    const float* upper    = (const float*)d_in[1];
    const float* basis    = (const float*)d_in[2];
    const float* z        = (const float*)d_in[3];
    const int*   is_input = (const int*)d_in[4];
    const float* vraw     = (const float*)d_in[5];
    const int*   perm     = (const int*)d_in[6];
    float* out = (float*)d_out;

    float* ws    = (float*)d_ws;
    float* Ct    = ws;                               // 730*730
    float* V     = Ct + (size_t)NF * NF;             // 8*730*32
    float* CactT = V + (size_t)BV * NF * KK;         // 8*448*448
    float* Wc    = CactT + (size_t)BV * AST * AST;   // 8*448*32
    float* Vact  = Wc + (size_t)BV * AST * KK;       // 8*448*32
    int*   act   = (int*)(Vact + (size_t)BV * AST * KK);  // 8*448
    int*   nAa   = act + BV * AST;                   // 8
    // total ws ≈ 10.3 MB

    build_C_kernel<<<dim3((NF * NF + 255) / 256), dim3(256), 0, stream>>>(coeff, upper, basis, Ct);
    init_V_kernel<<<dim3(730), dim3(256), 0, stream>>>(z, vraw, V);
    build_act_kernel<<<dim3(BV), dim3(64), 0, stream>>>(is_input, perm, act, nAa);
    gather_CactT_kernel<<<dim3(AST, BV), dim3(256), 0, stream>>>(Ct, act, CactT);
    init_W_kernel<<<dim3(AST / 8, BV), dim3(256), 0, stream>>>(Ct, act, nAa, V, Wc, Vact);
    mix_kernel<<<dim3(BV), dim3(MTH), 0, stream>>>(CactT, Wc, Vact, act, nAa, is_input, z, V, out);
}

// Round 12
// 742.988 us; speedup vs baseline: 15.3233x; 2.6665x over previous
//
#include <hip/hip_runtime.h>

#define NN   729
#define NF   730   // N+1
#define BV   8
#define KK   32
#define NBAS 40
#define MAXIT 10
#define PI_F 3.14159265358979323846f

#define MTH   512   // mix threads (8 waves; 512-thr kernels get ~124 VGPR budget)
#define BT    16    // steps per block
#define AST   448   // padded max active rows; CactT stride
#define CPST  20    // cpanel row stride (floats): 20 banks -> conflict-free b128

typedef float v2f __attribute__((ext_vector_type(2)));

__device__ __forceinline__ void fma4(float4& w, float c, const float4& d) {
    w.x = fmaf(c, d.x, w.x); w.y = fmaf(c, d.y, w.y);
    w.z = fmaf(c, d.z, w.z); w.w = fmaf(c, d.w, w.w);
}

// ---------------- build Ct (730x730), Ct[i][j] = C[j][i] ----------------
__global__ void build_C_kernel(const float* __restrict__ coeff,
                               const float* __restrict__ upper,
                               const float* __restrict__ basis,
                               float* __restrict__ Ct) {
    int idx = blockIdx.x * blockDim.x + threadIdx.x;
    if (idx >= NF * NF) return;
    int i = idx / NF, j = idx - i * NF;
    float val;
    if (i == 0) {
        val = (j == 0) ? 0.f : upper[j - 1];
    } else if (j == 0) {
        val = upper[i - 1];
    } else {
        float acc = 0.f;
        const float* bp = basis + (size_t)(i - 1) * NN + (j - 1);
        #pragma unroll 8
        for (int b = 0; b < NBAS; ++b)
            acc = fmaf(coeff[b], bp[(size_t)b * NN * NN], acc);
        val = acc;
    }
    Ct[(size_t)j * NF + i] = val;
}

// ---------------- init V  (B x 730 x 32) ----------------
__global__ void init_V_kernel(const float* __restrict__ z,
                              const float* __restrict__ vraw,
                              float* __restrict__ V) {
    int g = threadIdx.x >> 5;
    int k = threadIdx.x & 31;
    int row = blockIdx.x * 8 + g;           // 0..5839
    int b = row / NF, n = row - b * NF;
    const float* vr = vraw + (size_t)b * NF * KK;

    float v0 = vr[k];
    float s2 = v0 * v0;
    #pragma unroll
    for (int off = 16; off; off >>= 1) s2 += __shfl_xor(s2, off, 32);
    v0 = v0 / sqrtf(s2);

    float vn = vr[(size_t)n * KK + k];
    float d = vn * v0;
    #pragma unroll
    for (int off = 16; off; off >>= 1) d += __shfl_xor(d, off, 32);
    float u = vn - d * v0;
    float un2 = u * u;
    #pragma unroll
    for (int off = 16; off; off >>= 1) un2 += __shfl_xor(un2, off, 32);
    u = u / fmaxf(sqrtf(un2), 1e-8f);

    float zf = (n == 0) ? 1.f : z[b * NN + (n - 1)];
    float c = cosf(PI_F * zf), s = sinf(PI_F * zf);
    float outv = -c * v0 + s * u;
    if (n == 0) outv = v0;
    V[((size_t)b * NF + n) * KK + k] = outv;
}

// ---------------- build per-batch active lists (perm order) ----------------
__global__ void build_act_kernel(const int* __restrict__ is_input,
                                 const int* __restrict__ perm,
                                 int* __restrict__ act, int* __restrict__ nA_arr) {
    int b = blockIdx.x, l = threadIdx.x;   // 64 threads = 1 wave
    int base = 0;
    for (int c = 0; c < (NN + 63) / 64; ++c) {
        int idx = c * 64 + l;
        bool f = false; int pi = 0;
        if (idx < NN) { pi = perm[idx]; f = (is_input[b * NN + pi - 1] == 0); }
        unsigned long long m = __ballot(f);
        int pos = __popcll(m & ((1ull << l) - 1ull));
        if (f && base + pos < AST) act[b * AST + base + pos] = pi;
        base += __popcll(m);
    }
    if (base > AST) base = AST;
    if (l == 0) nA_arr[b] = base;
    for (int p = base + l; p < AST; p += 64) act[b * AST + p] = 0;
}

// --- gather CactT[b][a][t] = C[r_t][r_a] = Ct[r_a][r_t] (row-coalesced) ---
__global__ void gather_CactT_kernel(const float* __restrict__ Ct,
                                    const int* __restrict__ act,
                                    float* __restrict__ CactT) {
    int a = blockIdx.x, b = blockIdx.y;
    __shared__ int acts[AST];
    for (int i = threadIdx.x; i < AST; i += blockDim.x) acts[i] = act[b * AST + i];
    __syncthreads();
    const float* src = Ct + (size_t)acts[a] * NF;
    float* dst = CactT + ((size_t)b * AST + a) * AST;
    for (int t = threadIdx.x; t < AST; t += blockDim.x)
        dst[t] = src[acts[t]];
}

// --- init W compact + compact V copy ---
__global__ void init_W_kernel(const float* __restrict__ Ct,
                              const int* __restrict__ act,
                              const int* __restrict__ nA_arr,
                              const float* __restrict__ V,
                              float* __restrict__ Wc,
                              float* __restrict__ Vact) {
    int b = blockIdx.y;
    int a = blockIdx.x * 8 + (threadIdx.x >> 5);
    int k = threadIdx.x & 31;
    int nA = nA_arr[b];
    float w = 0.f;
    int ra = act[b * AST + a];
    float vv = V[((size_t)b * NF + ra) * KK + k];
    if (a < nA) {
        const float* ctr = Ct + (size_t)ra * NF;
        const float* vb = V + (size_t)b * NF * KK + k;
        float acc = 0.f;
        for (int j = 0; j < NF; ++j)
            acc = fmaf(ctr[j], vb[(size_t)j * KK], acc);
        w = acc - ctr[ra] * vv;
    }
    Wc[((size_t)b * AST + a) * KK + k] = w;
    Vact[((size_t)b * AST + a) * KK + k] = vv;
}

// 16-lane row sum via DPP row rotations (pure VALU)
__device__ __forceinline__ float rowsum16(float x) {
    int y;
    y = __builtin_amdgcn_update_dpp(0, __float_as_int(x), 0x121, 0xF, 0xF, false);
    x += __int_as_float(y);
    y = __builtin_amdgcn_update_dpp(0, __float_as_int(x), 0x122, 0xF, 0xF, false);
    x += __int_as_float(y);
    y = __builtin_amdgcn_update_dpp(0, __float_as_int(x), 0x124, 0xF, 0xF, false);
    x += __int_as_float(y);
    y = __builtin_amdgcn_update_dpp(0, __float_as_int(x), 0x128, 0xF, 0xF, false);
    x += __int_as_float(y);
    return x;
}

// ------- mixing: W in bulk registers, cpanel LDS-staged, 512 threads -------
__global__ __launch_bounds__(MTH, 2)
void mix_kernel(const float* __restrict__ CactT_g,
                const float* __restrict__ Wc_g,
                const float* __restrict__ Vact_g,
                const int* __restrict__ act_g,
                const int* __restrict__ nA_arr,
                const int* __restrict__ is_input,
                const float* __restrict__ z,
                const float* __restrict__ Vg,
                float* __restrict__ out) {
    __shared__ __align__(16) float V_c[AST * KK];         // 57344 B
    __shared__ __align__(16) float cpanel[2][AST * CPST]; // 71680 B
    __shared__ __align__(16) float dv_s[2][BT * KK];      // 4096 B
    __shared__ __align__(16) float gpub[BT * KK];         // 2048 B
    __shared__ __align__(16) float cblk_s[2][BT * BT];    // 2048 B
    __shared__ __align__(16) float cmini_s[2][BT * BT];   // 2048 B
    __shared__ float Cd_s[AST];                           // 1792 B
    __shared__ int   slot_s[NF];                          // 2920 B

    int b = blockIdx.x, tid = threadIdx.x;
    const float* CT = CactT_g + (size_t)b * AST * AST;
    const float* Vact = Vact_g + (size_t)b * AST * KK;
    int nA = nA_arr[b];
    int nblkp = (nA + BT - 1) / BT;
    if (nblkp < 2) nblkp = 2;
    int nAp = nblkp * BT;
    int totB = MAXIT * nblkp;

    int wid = tid >> 6;
    int l64 = tid & 63;
    int lane = tid - 64;          // bulk lane 0..447 (valid when wid>=1)
    int kq = lane & 7;            // k-quad: floats 4kq..4kq+3
    int rslot = lane >> 3;        // 0..55; rows rslot + 56p
    int kp = tid & 15;            // serial k-pair

    // ---- setup ----
    for (int idx = tid; idx < AST * 8; idx += MTH)
        ((float4*)V_c)[idx] = ((const float4*)Vact)[idx];
    if (tid < AST) Cd_s[tid] = CT[(size_t)tid * AST + tid];
    if (tid < nA) slot_s[act_g[b * AST + tid]] = tid;
    if (tid < 256) {   // cblk for block 0
        int t = tid >> 4, u = tid & 15;
        cblk_s[0][t * BT + u] = CT[(size_t)u * AST + t];
    }
    // W rows into registers
    float4 w[8];
    #pragma unroll
    for (int p = 0; p < 8; ++p) {
        float4 zz = {0.f, 0.f, 0.f, 0.f};
        w[p] = zz;
        if (wid >= 1)
            w[p] = *(const float4*)&Wc_g[((size_t)b * AST + rslot + 56 * p) * KK + 4 * kq];
    }
    __syncthreads();

    for (int bi = 0; bi < totB; ++bi) {
        int blk = bi % nblkp, s0 = blk * BT;
        int pblk = (bi - 1 + nblkp) % nblkp, sp0 = pblk * BT;  // junk at bi=0
        int cb = bi & 1, pv = cb ^ 1;
        int sn0 = ((bi + 1) % nblkp) * BT;

        float4 st0, st1, st2, st3;
        // ---- phase 1 ----
        if (wid >= 1) {
            // issue next-iter cpanel loads (cols = this block's s0)
            const float* srcp = CT + (size_t)lane * AST + s0;
            st0 = *(const float4*)(srcp);
            st1 = *(const float4*)(srcp + 4);
            st2 = *(const float4*)(srcp + 8);
            st3 = *(const float4*)(srcp + 12);
            // owners of current block rows: apply prev dv (cmini) + publish
            #pragma unroll
            for (int p = 0; p < 8; ++p) {
                int a = rslot + 56 * p;
                if ((a >> 4) == blk) {
                    int u = a - s0;
                    if (bi > 0) {
                        #pragma unroll
                        for (int q = 0; q < 4; ++q) {
                            float4 cm = *(const float4*)&cmini_s[cb][u * BT + 4 * q];
                            float4 d;
                            d = *(const float4*)&dv_s[pv][(4*q+0) * KK + 4 * kq];
                            fma4(w[p], cm.x, d);
                            d = *(const float4*)&dv_s[pv][(4*q+1) * KK + 4 * kq];
                            fma4(w[p], cm.y, d);
                            d = *(const float4*)&dv_s[pv][(4*q+2) * KK + 4 * kq];
                            fma4(w[p], cm.z, d);
                            d = *(const float4*)&dv_s[pv][(4*q+3) * KK + 4 * kq];
                            fma4(w[p], cm.w, d);
                        }
                    }
                    *(float4*)&gpub[u * KK + 4 * kq] = w[p];
                }
            }
        }
        __syncthreads();

        // ---- phase 2: serial (wave 0) || bulk (waves 1-7) ----
        if (wid == 0) {
            float g0[BT], g1[BT], vo0[BT], vo1[BT];
            #pragma unroll
            for (int u = 0; u < BT; ++u) {
                v2f gv = *(const v2f*)&gpub[u * KK + 2 * kp];
                g0[u] = gv.x; g1[u] = gv.y;
                v2f vv = *(const v2f*)&V_c[(s0 + u) * KK + 2 * kp];
                vo0[u] = vv.x; vo1[u] = vv.y;
            }
            #pragma unroll
            for (int u = 0; u < BT; ++u) {
                int s = s0 + u;
                float n2 = fmaf(g0[u], g0[u], g1[u] * g1[u]);
                n2 = rowsum16(n2);
                float inv = -__builtin_amdgcn_rsqf(fmaxf(n2, 1e-16f));
                float msk = (s < nA) ? 1.f : 0.f;
                float d0 = fmaf(g0[u], inv, -vo0[u]) * msk;
                float d1 = fmaf(g1[u], inv, -vo1[u]) * msk;
                if (tid < 16) {
                    v2f dv2; dv2.x = d0; dv2.y = d1;
                    *(v2f*)&dv_s[cb][u * KK + 2 * kp] = dv2;
                    v2f vn2; vn2.x = vo0[u] + d0; vn2.y = vo1[u] + d1;
                    *(v2f*)&V_c[s * KK + 2 * kp] = vn2;
                }
                #pragma unroll
                for (int u2 = u + 1; u2 < BT; ++u2) {
                    float c = cblk_s[cb][u * BT + u2];
                    g0[u2] = fmaf(c, d0, g0[u2]);
                    g1[u2] = fmaf(c, d1, g1[u2]);
                }
            }
        } else {
            // bulk: rank-16 in two rank-8 halves, c from cpanel[cb]
            if (bi > 0) {
                #pragma unroll
                for (int h = 0; h < 2; ++h) {
                    float4 dvv[8];
                    #pragma unroll
                    for (int t = 0; t < 8; ++t)
                        dvv[t] = *(const float4*)&dv_s[pv][(8 * h + t) * KK + 4 * kq];
                    #pragma unroll
                    for (int p = 0; p < 8; ++p) {
                        int a = rslot + 56 * p;
                        if (a < nAp && (a >> 4) != blk) {
                            float4 cA = *(const float4*)&cpanel[cb][a * CPST + 8 * h];
                            float4 cB = *(const float4*)&cpanel[cb][a * CPST + 8 * h + 4];
                            fma4(w[p], cA.x, dvv[0]);
                            fma4(w[p], cA.y, dvv[1]);
                            fma4(w[p], cA.z, dvv[2]);
                            fma4(w[p], cA.w, dvv[3]);
                            fma4(w[p], cB.x, dvv[4]);
                            fma4(w[p], cB.y, dvv[5]);
                            fma4(w[p], cB.z, dvv[6]);
                            fma4(w[p], cB.w, dvv[7]);
                        }
                    }
                }
                // diag self-cancel for rows of the previous block
                #pragma unroll
                for (int p = 0; p < 8; ++p) {
                    int a = rslot + 56 * p;
                    if ((a >> 4) == pblk) {
                        float4 dd = *(const float4*)&dv_s[pv][(a - sp0) * KK + 4 * kq];
                        fma4(w[p], -Cd_s[a], dd);
                    }
                }
            }
            // write staged cpanel (late)
            {
                float* dst = &cpanel[pv][lane * CPST];
                *(float4*)(dst)      = st0;
                *(float4*)(dst + 4)  = st1;
                *(float4*)(dst + 8)  = st2;
                *(float4*)(dst + 12) = st3;
            }
            if (wid == 7) {
                // cmini[pv]: rows of next block x cols of this block
                {
                    int u = l64 & 15, q = l64 >> 4;
                    float4 v = *(const float4*)&CT[(size_t)(sn0 + u) * AST + s0 + 4 * q];
                    *(float4*)&cmini_s[pv][u * BT + 4 * q] = v;
                }
                // cblk[pv]: next block's intra tile (transposed store)
                {
                    int u = l64 & 15, q = l64 >> 4;
                    float4 v = *(const float4*)&CT[(size_t)(sn0 + u) * AST + sn0 + 4 * q];
                    cblk_s[pv][(4 * q + 0) * BT + u] = v.x;
                    cblk_s[pv][(4 * q + 1) * BT + u] = v.y;
                    cblk_s[pv][(4 * q + 2) * BT + u] = v.z;
                    cblk_s[pv][(4 * q + 3) * BT + u] = v.w;
                }
            }
        }
        __syncthreads();
    }

    // ---- epilogue: z_out ----
    int k = tid & 31, r = tid >> 5;   // r in 0..15
    float v0k = Vg[(size_t)b * NF * KK + k];
    for (int n = 1 + r; n <= NN; n += 16) {
        int ii = is_input[b * NN + n - 1];
        float res;
        if (ii == 1) {
            res = z[b * NN + n - 1];
        } else {
            int a = slot_s[n];
            float dot = V_c[a * KK + k] * v0k;
            #pragma unroll
            for (int off = 16; off; off >>= 1) dot += __shfl_xor(dot, off, 32);
            float ca = fminf(fmaxf(-dot, -1.f + 1e-6f), 1.f - 1e-6f);
            res = acosf(ca) * (1.f / PI_F);
        }
        if (k == 0) out[b * NN + n - 1] = res;
    }
}

extern "C" void kernel_launch(void* const* d_in, const int* in_sizes, int n_in,
                              void* d_out, int out_size, void* d_ws, size_t ws_size,
                              hipStream_t stream) {
    const float* coeff    = (const float*)d_in[0];
    const float* upper    = (const float*)d_in[1];
    const float* basis    = (const float*)d_in[2];
    const float* z        = (const float*)d_in[3];
    const int*   is_input = (const int*)d_in[4];
    const float* vraw     = (const float*)d_in[5];
    const int*   perm     = (const int*)d_in[6];
    float* out = (float*)d_out;

    float* ws    = (float*)d_ws;
    float* Ct    = ws;                               // 730*730
    float* V     = Ct + (size_t)NF * NF;             // 8*730*32
    float* CactT = V + (size_t)BV * NF * KK;         // 8*448*448
    float* Wc    = CactT + (size_t)BV * AST * AST;   // 8*448*32
    float* Vact  = Wc + (size_t)BV * AST * KK;       // 8*448*32
    int*   act   = (int*)(Vact + (size_t)BV * AST * KK);  // 8*448
    int*   nAa   = act + BV * AST;                   // 8
    // total ws ≈ 10.3 MB

    build_C_kernel<<<dim3((NF * NF + 255) / 256), dim3(256), 0, stream>>>(coeff, upper, basis, Ct);
    init_V_kernel<<<dim3(730), dim3(256), 0, stream>>>(z, vraw, V);
    build_act_kernel<<<dim3(BV), dim3(64), 0, stream>>>(is_input, perm, act, nAa);
    gather_CactT_kernel<<<dim3(AST, BV), dim3(256), 0, stream>>>(Ct, act, CactT);
    init_W_kernel<<<dim3(AST / 8, BV), dim3(256), 0, stream>>>(Ct, act, nAa, V, Wc, Vact);
    mix_kernel<<<dim3(BV), dim3(MTH), 0, stream>>>(CactT, Wc, Vact, act, nAa, is_input, z, V, out);
}

// Round 13
// 738.808 us; speedup vs baseline: 15.4100x; 1.0057x over previous
//
#include <hip/hip_runtime.h>

#define NN   729
#define NF   730   // N+1
#define BV   8
#define KK   32
#define NBAS 40
#define MAXIT 10
#define PI_F 3.14159265358979323846f

#define MTH   512   // mix threads (8 waves; 512-thr kernels get ~124 VGPR budget)
#define BT    16    // steps per block
#define AST   448   // padded max active rows; CactT stride

typedef float v2f __attribute__((ext_vector_type(2)));

__device__ __forceinline__ void fma4(float4& w, float c, const float4& d) {
    w.x = fmaf(c, d.x, w.x); w.y = fmaf(c, d.y, w.y);
    w.z = fmaf(c, d.z, w.z); w.w = fmaf(c, d.w, w.w);
}

// ---------------- build Ct (730x730), Ct[i][j] = C[j][i] ----------------
__global__ void build_C_kernel(const float* __restrict__ coeff,
                               const float* __restrict__ upper,
                               const float* __restrict__ basis,
                               float* __restrict__ Ct) {
    int idx = blockIdx.x * blockDim.x + threadIdx.x;
    if (idx >= NF * NF) return;
    int i = idx / NF, j = idx - i * NF;
    float val;
    if (i == 0) {
        val = (j == 0) ? 0.f : upper[j - 1];
    } else if (j == 0) {
        val = upper[i - 1];
    } else {
        float acc = 0.f;
        const float* bp = basis + (size_t)(i - 1) * NN + (j - 1);
        #pragma unroll 8
        for (int b = 0; b < NBAS; ++b)
            acc = fmaf(coeff[b], bp[(size_t)b * NN * NN], acc);
        val = acc;
    }
    Ct[(size_t)j * NF + i] = val;
}

// ---------------- init V  (B x 730 x 32) ----------------
__global__ void init_V_kernel(const float* __restrict__ z,
                              const float* __restrict__ vraw,
                              float* __restrict__ V) {
    int g = threadIdx.x >> 5;
    int k = threadIdx.x & 31;
    int row = blockIdx.x * 8 + g;           // 0..5839
    int b = row / NF, n = row - b * NF;
    const float* vr = vraw + (size_t)b * NF * KK;

    float v0 = vr[k];
    float s2 = v0 * v0;
    #pragma unroll
    for (int off = 16; off; off >>= 1) s2 += __shfl_xor(s2, off, 32);
    v0 = v0 / sqrtf(s2);

    float vn = vr[(size_t)n * KK + k];
    float d = vn * v0;
    #pragma unroll
    for (int off = 16; off; off >>= 1) d += __shfl_xor(d, off, 32);
    float u = vn - d * v0;
    float un2 = u * u;
    #pragma unroll
    for (int off = 16; off; off >>= 1) un2 += __shfl_xor(un2, off, 32);
    u = u / fmaxf(sqrtf(un2), 1e-8f);

    float zf = (n == 0) ? 1.f : z[b * NN + (n - 1)];
    float c = cosf(PI_F * zf), s = sinf(PI_F * zf);
    float outv = -c * v0 + s * u;
    if (n == 0) outv = v0;
    V[((size_t)b * NF + n) * KK + k] = outv;
}

// ---------------- build per-batch active lists (perm order) ----------------
__global__ void build_act_kernel(const int* __restrict__ is_input,
                                 const int* __restrict__ perm,
                                 int* __restrict__ act, int* __restrict__ nA_arr) {
    int b = blockIdx.x, l = threadIdx.x;   // 64 threads = 1 wave
    int base = 0;
    for (int c = 0; c < (NN + 63) / 64; ++c) {
        int idx = c * 64 + l;
        bool f = false; int pi = 0;
        if (idx < NN) { pi = perm[idx]; f = (is_input[b * NN + pi - 1] == 0); }
        unsigned long long m = __ballot(f);
        int pos = __popcll(m & ((1ull << l) - 1ull));
        if (f && base + pos < AST) act[b * AST + base + pos] = pi;
        base += __popcll(m);
    }
    if (base > AST) base = AST;
    if (l == 0) nA_arr[b] = base;
    for (int p = base + l; p < AST; p += 64) act[b * AST + p] = 0;
}

// --- gather CactT[b][a][t] = C[r_t][r_a] = Ct[r_a][r_t] (row-coalesced) ---
__global__ void gather_CactT_kernel(const float* __restrict__ Ct,
                                    const int* __restrict__ act,
                                    float* __restrict__ CactT) {
    int a = blockIdx.x, b = blockIdx.y;
    __shared__ int acts[AST];
    for (int i = threadIdx.x; i < AST; i += blockDim.x) acts[i] = act[b * AST + i];
    __syncthreads();
    const float* src = Ct + (size_t)acts[a] * NF;
    float* dst = CactT + ((size_t)b * AST + a) * AST;
    for (int t = threadIdx.x; t < AST; t += blockDim.x)
        dst[t] = src[acts[t]];
}

// --- init W compact + compact V copy ---
__global__ void init_W_kernel(const float* __restrict__ Ct,
                              const int* __restrict__ act,
                              const int* __restrict__ nA_arr,
                              const float* __restrict__ V,
                              float* __restrict__ Wc,
                              float* __restrict__ Vact) {
    int b = blockIdx.y;
    int a = blockIdx.x * 8 + (threadIdx.x >> 5);
    int k = threadIdx.x & 31;
    int nA = nA_arr[b];
    float w = 0.f;
    int ra = act[b * AST + a];
    float vv = V[((size_t)b * NF + ra) * KK + k];
    if (a < nA) {
        const float* ctr = Ct + (size_t)ra * NF;
        const float* vb = V + (size_t)b * NF * KK + k;
        float acc = 0.f;
        for (int j = 0; j < NF; ++j)
            acc = fmaf(ctr[j], vb[(size_t)j * KK], acc);
        w = acc - ctr[ra] * vv;
    }
    Wc[((size_t)b * AST + a) * KK + k] = w;
    Vact[((size_t)b * AST + a) * KK + k] = vv;
}

// 16-lane row sum via DPP row rotations (pure VALU)
__device__ __forceinline__ float rowsum16(float x) {
    int y;
    y = __builtin_amdgcn_update_dpp(0, __float_as_int(x), 0x121, 0xF, 0xF, false);
    x += __int_as_float(y);
    y = __builtin_amdgcn_update_dpp(0, __float_as_int(x), 0x122, 0xF, 0xF, false);
    x += __int_as_float(y);
    y = __builtin_amdgcn_update_dpp(0, __float_as_int(x), 0x124, 0xF, 0xF, false);
    x += __int_as_float(y);
    y = __builtin_amdgcn_update_dpp(0, __float_as_int(x), 0x128, 0xF, 0xF, false);
    x += __int_as_float(y);
    return x;
}

// -- mixing: W in bulk registers, c direct from L1/L2, 512 threads --
__global__ __launch_bounds__(MTH, 2)
void mix_kernel(const float* __restrict__ CactT_g,
                const float* __restrict__ Wc_g,
                const float* __restrict__ Vact_g,
                const int* __restrict__ act_g,
                const int* __restrict__ nA_arr,
                const int* __restrict__ is_input,
                const float* __restrict__ z,
                const float* __restrict__ Vg,
                float* __restrict__ out) {
    __shared__ __align__(16) float V_c[AST * KK];       // 57344 B
    __shared__ __align__(16) float dv_s[2][BT * KK];    // 4096 B
    __shared__ __align__(16) float gpub[BT * KK];       // 2048 B
    __shared__ __align__(16) float cblk_s[2][BT * BT];  // 2048 B
    __shared__ float Cd_s[AST];                         // 1792 B
    __shared__ int   slot_s[NF];                        // 2920 B
    __shared__ float ldspad[3200];                      // pad -> LDS > 80 KB (1 blk/CU)

    int b = blockIdx.x, tid = threadIdx.x;
    const float* CT = CactT_g + (size_t)b * AST * AST;
    const float* Vact = Vact_g + (size_t)b * AST * KK;
    int nA = nA_arr[b];
    int nblkp = (nA + BT - 1) / BT;
    if (nblkp < 2) nblkp = 2;
    int nAp = nblkp * BT;
    int totB = MAXIT * nblkp;

    int wid = tid >> 6;
    int l64 = tid & 63;
    int lane = tid - 64;          // bulk lane 0..447 (valid when wid>=1)
    int kq = lane & 7;            // k-quad: floats 4kq..4kq+3
    int rslot = lane >> 3;        // 0..55; rows rslot + 56p
    int kp = tid & 15;            // serial k-pair

    // ---- setup ----
    for (int idx = tid; idx < AST * 8; idx += MTH)
        ((float4*)V_c)[idx] = ((const float4*)Vact)[idx];
    if (tid < AST) Cd_s[tid] = CT[(size_t)tid * AST + tid];
    if (tid < nA) slot_s[act_g[b * AST + tid]] = tid;
    if (tid < 256) {   // cblk for block 0: cblk[x][y] = C[r_x][r_y]
        int t = tid >> 4, u = tid & 15;
        cblk_s[0][t * BT + u] = CT[(size_t)u * AST + t];
    }
    if (tid == 0) ldspad[3199] = 0.f;   // keep pad alive
    // W rows into registers
    float4 w[8];
    #pragma unroll
    for (int p = 0; p < 8; ++p) {
        float4 zz = {0.f, 0.f, 0.f, 0.f};
        w[p] = zz;
        if (wid >= 1)
            w[p] = *(const float4*)&Wc_g[((size_t)b * AST + rslot + 56 * p) * KK + 4 * kq];
    }
    __syncthreads();

    for (int bi = 0; bi < totB; ++bi) {
        int blk = bi % nblkp, s0 = blk * BT;
        int pblk = (bi - 1 + nblkp) % nblkp, sp0 = pblk * BT;  // junk at bi=0
        int cb = bi & 1, pv = cb ^ 1;
        int sn0 = ((bi + 1) % nblkp) * BT;

        // ---- phase 1: owners of current block apply prev dv + publish ----
        if (wid >= 1) {
            #pragma unroll
            for (int p = 0; p < 8; ++p) {
                int a = rslot + 56 * p;
                if ((a >> 4) == blk) {
                    int u = a - s0;
                    if (bi > 0) {
                        const float* cr = CT + (size_t)a * AST + sp0;
                        float4 c0 = *(const float4*)(cr);
                        float4 c1 = *(const float4*)(cr + 4);
                        float4 c2 = *(const float4*)(cr + 8);
                        float4 c3 = *(const float4*)(cr + 12);
                        float4 d;
                        d = *(const float4*)&dv_s[pv][0  * KK + 4 * kq]; fma4(w[p], c0.x, d);
                        d = *(const float4*)&dv_s[pv][1  * KK + 4 * kq]; fma4(w[p], c0.y, d);
                        d = *(const float4*)&dv_s[pv][2  * KK + 4 * kq]; fma4(w[p], c0.z, d);
                        d = *(const float4*)&dv_s[pv][3  * KK + 4 * kq]; fma4(w[p], c0.w, d);
                        d = *(const float4*)&dv_s[pv][4  * KK + 4 * kq]; fma4(w[p], c1.x, d);
                        d = *(const float4*)&dv_s[pv][5  * KK + 4 * kq]; fma4(w[p], c1.y, d);
                        d = *(const float4*)&dv_s[pv][6  * KK + 4 * kq]; fma4(w[p], c1.z, d);
                        d = *(const float4*)&dv_s[pv][7  * KK + 4 * kq]; fma4(w[p], c1.w, d);
                        d = *(const float4*)&dv_s[pv][8  * KK + 4 * kq]; fma4(w[p], c2.x, d);
                        d = *(const float4*)&dv_s[pv][9  * KK + 4 * kq]; fma4(w[p], c2.y, d);
                        d = *(const float4*)&dv_s[pv][10 * KK + 4 * kq]; fma4(w[p], c2.z, d);
                        d = *(const float4*)&dv_s[pv][11 * KK + 4 * kq]; fma4(w[p], c2.w, d);
                        d = *(const float4*)&dv_s[pv][12 * KK + 4 * kq]; fma4(w[p], c3.x, d);
                        d = *(const float4*)&dv_s[pv][13 * KK + 4 * kq]; fma4(w[p], c3.y, d);
                        d = *(const float4*)&dv_s[pv][14 * KK + 4 * kq]; fma4(w[p], c3.z, d);
                        d = *(const float4*)&dv_s[pv][15 * KK + 4 * kq]; fma4(w[p], c3.w, d);
                    }
                    *(float4*)&gpub[u * KK + 4 * kq] = w[p];
                }
            }
        }
        __syncthreads();

        // ---- phase 2: serial (wave 0) || bulk (waves 1-7) ----
        if (wid == 0) {
            float g0[BT], g1[BT], vo0[BT], vo1[BT];
            #pragma unroll
            for (int u = 0; u < BT; ++u) {
                v2f gv = *(const v2f*)&gpub[u * KK + 2 * kp];
                g0[u] = gv.x; g1[u] = gv.y;
                v2f vv = *(const v2f*)&V_c[(s0 + u) * KK + 2 * kp];
                vo0[u] = vv.x; vo1[u] = vv.y;
            }
            #pragma unroll
            for (int u = 0; u < BT; ++u) {
                int s = s0 + u;
                float n2 = fmaf(g0[u], g0[u], g1[u] * g1[u]);
                n2 = rowsum16(n2);
                float inv = -__builtin_amdgcn_rsqf(fmaxf(n2, 1e-16f));
                float msk = (s < nA) ? 1.f : 0.f;
                float d0 = fmaf(g0[u], inv, -vo0[u]) * msk;
                float d1 = fmaf(g1[u], inv, -vo1[u]) * msk;
                if (tid < 16) {
                    v2f dv2; dv2.x = d0; dv2.y = d1;
                    *(v2f*)&dv_s[cb][u * KK + 2 * kp] = dv2;
                    v2f vn2; vn2.x = vo0[u] + d0; vn2.y = vo1[u] + d1;
                    *(v2f*)&V_c[s * KK + 2 * kp] = vn2;
                }
                #pragma unroll
                for (int u2 = u + 1; u2 < BT; ++u2) {
                    float c = cblk_s[cb][u * BT + u2];
                    g0[u2] = fmaf(c, d0, g0[u2]);
                    g1[u2] = fmaf(c, d1, g1[u2]);
                }
            }
        } else {
            if (wid == 7) {   // stage next block's intra tile (for serial)
                int u = l64 & 15, q = l64 >> 4;
                float4 v = *(const float4*)&CT[(size_t)(sn0 + u) * AST + sn0 + 4 * q];
                cblk_s[pv][(4 * q + 0) * BT + u] = v.x;
                cblk_s[pv][(4 * q + 1) * BT + u] = v.y;
                cblk_s[pv][(4 * q + 2) * BT + u] = v.z;
                cblk_s[pv][(4 * q + 3) * BT + u] = v.w;
            }
            // bulk: rank-16 in two rank-8 halves; c direct from L1/L2,
            // ping-pong prefetched one pass ahead
            if (bi > 0) {
                #pragma unroll
                for (int h = 0; h < 2; ++h) {
                    float4 dvv[8];
                    #pragma unroll
                    for (int t = 0; t < 8; ++t)
                        dvv[t] = *(const float4*)&dv_s[pv][(8 * h + t) * KK + 4 * kq];
                    float4 cA0, cB0, cA1, cB1;
                    {
                        const float* cr = CT + (size_t)rslot * AST + sp0 + 8 * h;
                        cA0 = *(const float4*)(cr);
                        cB0 = *(const float4*)(cr + 4);
                    }
                    #pragma unroll
                    for (int p = 0; p < 8; ++p) {
                        int a = rslot + 56 * p;
                        if (p < 7) {   // prefetch next pass's c
                            const float* cr = CT + (size_t)(a + 56) * AST + sp0 + 8 * h;
                            if (p & 1) { cA0 = *(const float4*)(cr); cB0 = *(const float4*)(cr + 4); }
                            else       { cA1 = *(const float4*)(cr); cB1 = *(const float4*)(cr + 4); }
                        }
                        float4 ca = (p & 1) ? cA1 : cA0;
                        float4 cbq = (p & 1) ? cB1 : cB0;
                        if (a < nAp && (a >> 4) != blk) {
                            fma4(w[p], ca.x,  dvv[0]);
                            fma4(w[p], ca.y,  dvv[1]);
                            fma4(w[p], ca.z,  dvv[2]);
                            fma4(w[p], ca.w,  dvv[3]);
                            fma4(w[p], cbq.x, dvv[4]);
                            fma4(w[p], cbq.y, dvv[5]);
                            fma4(w[p], cbq.z, dvv[6]);
                            fma4(w[p], cbq.w, dvv[7]);
                        }
                    }
                }
                // diag self-cancel for rows of the previous block
                #pragma unroll
                for (int p = 0; p < 8; ++p) {
                    int a = rslot + 56 * p;
                    if ((a >> 4) == pblk) {
                        float4 dd = *(const float4*)&dv_s[pv][(a - sp0) * KK + 4 * kq];
                        fma4(w[p], -Cd_s[a], dd);
                    }
                }
            }
        }
        __syncthreads();
    }

    // ---- epilogue: z_out ----
    int k = tid & 31, r = tid >> 5;   // r in 0..15
    float v0k = Vg[(size_t)b * NF * KK + k];
    for (int n = 1 + r; n <= NN; n += 16) {
        int ii = is_input[b * NN + n - 1];
        float res;
        if (ii == 1) {
            res = z[b * NN + n - 1];
        } else {
            int a = slot_s[n];
            float dot = V_c[a * KK + k] * v0k;
            #pragma unroll
            for (int off = 16; off; off >>= 1) dot += __shfl_xor(dot, off, 32);
            float ca = fminf(fmaxf(-dot, -1.f + 1e-6f), 1.f - 1e-6f);
            res = acosf(ca) * (1.f / PI_F);
        }
        if (k == 0) out[b * NN + n - 1] = res;
    }
}

extern "C" void kernel_launch(void* const* d_in, const int* in_sizes, int n_in,
                              void* d_out, int out_size, void* d_ws, size_t ws_size,
                              hipStream_t stream) {
    const float* coeff    = (const float*)d_in[0];
    const float* upper    = (const float*)d_in[1];
    const float* basis    = (const float*)d_in[2];
    const float* z        = (const float*)d_in[3];
    const int*   is_input = (const int*)d_in[4];
    const float* vraw     = (const float*)d_in[5];
    const int*   perm     = (const int*)d_in[6];
    float* out = (float*)d_out;

    float* ws    = (float*)d_ws;
    float* Ct    = ws;                               // 730*730
    float* V     = Ct + (size_t)NF * NF;             // 8*730*32
    float* CactT = V + (size_t)BV * NF * KK;         // 8*448*448
    float* Wc    = CactT + (size_t)BV * AST * AST;   // 8*448*32
    float* Vact  = Wc + (size_t)BV * AST * KK;       // 8*448*32
    int*   act   = (int*)(Vact + (size_t)BV * AST * KK);  // 8*448
    int*   nAa   = act + BV * AST;                   // 8
    // total ws ≈ 10.3 MB

    build_C_kernel<<<dim3((NF * NF + 255) / 256), dim3(256), 0, stream>>>(coeff, upper, basis, Ct);
    init_V_kernel<<<dim3(730), dim3(256), 0, stream>>>(z, vraw, V);
    build_act_kernel<<<dim3(BV), dim3(64), 0, stream>>>(is_input, perm, act, nAa);
    gather_CactT_kernel<<<dim3(AST, BV), dim3(256), 0, stream>>>(Ct, act, CactT);
    init_W_kernel<<<dim3(AST / 8, BV), dim3(256), 0, stream>>>(Ct, act, nAa, V, Wc, Vact);
    mix_kernel<<<dim3(BV), dim3(MTH), 0, stream>>>(CactT, Wc, Vact, act, nAa, is_input, z, V, out);
}